// Round 1
// 1032.384 us; speedup vs baseline: 1.0324x; 1.0324x over previous
//
#include <hip/hip_runtime.h>
#include <cstdint>
#include <cstddef>

// Problem constants (fixed by the reference)
#define B_ROWS 8192
#define E_EXP  8

typedef unsigned short ushort_t;
typedef short bf16x8 __attribute__((ext_vector_type(8)));
typedef float f32x4  __attribute__((ext_vector_type(4)));

__device__ __forceinline__ ushort_t f2b(float f) {
  union { float f; unsigned int i; } v; v.f = f;
  unsigned int u = v.i;
  unsigned int r = (u + 0x7fffu + ((u >> 16) & 1u)) >> 16;
  return (ushort_t)r;
}
__device__ __forceinline__ float eluf(float x) {
  return x > 0.f ? x : (__expf(x) - 1.f);
}

// ---------------------------------------------------------------------------
// Weight transpose + fp32->bf16: w flat [R][C] -> wT [C][R] bf16.
// block (64,16), grid (C/64, R/64). All dims divisible by 64 here.
// ---------------------------------------------------------------------------
__global__ void transpose_k(const float* __restrict__ src,
                            ushort_t* __restrict__ dst, int R, int C) {
  __shared__ ushort_t tile[64][65];
  int c0 = blockIdx.x * 64, r0 = blockIdx.y * 64;
  int x = threadIdx.x, y = threadIdx.y;
#pragma unroll
  for (int i = 0; i < 4; ++i)
    tile[y + 16 * i][x] = f2b(src[(size_t)(r0 + y + 16 * i) * C + c0 + x]);
  __syncthreads();
#pragma unroll
  for (int i = 0; i < 4; ++i)
    dst[(size_t)(c0 + y + 16 * i) * R + r0 + x] = tile[x][y + 16 * i];
}

// ---------------------------------------------------------------------------
// Gating MLP (pure fp32): coeff[b,e] = softmax(elu(elu(x@g0)@g1)@g2)
// Round 7: also emits Horner boundary-scale arrays for the expert-split GEMM:
//   rat2[b][e]: split {0-3},{4-7} -> e in {0,1,2,4,5,6}: c_e/c_{e+1};
//               e in {3,7}: c_e  (subset-final scale)
//   rat4[b][e]: split {0,1},{2,3},{4,5},{6,7} -> e even: c_e/c_{e+1}; odd: c_e
// ---------------------------------------------------------------------------
__global__ __launch_bounds__(128) void gate_k(
    const float* __restrict__ z, const float* __restrict__ c,
    const float* __restrict__ g0w, const float* __restrict__ g0b,
    const float* __restrict__ g1w, const float* __restrict__ g1b,
    const float* __restrict__ g2w, const float* __restrict__ g2b,
    float* __restrict__ coeff, float* __restrict__ rat2,
    float* __restrict__ rat4) {
  __shared__ float xs[4][320];
  __shared__ float h1[4][128];
  __shared__ float h2[4][128];
  __shared__ float lg[4][8];
  __shared__ float pr[4][8];
  int t = threadIdx.x;
  int r0 = blockIdx.x * 4;
  for (int idx = t; idx < 4 * 320; idx += 128) {
    int r = idx / 320, j = idx % 320;
    xs[r][j] = (j < 64) ? z[(size_t)(r0 + r) * 64 + j]
                        : c[(size_t)(r0 + r) * 256 + j - 64];
  }
  __syncthreads();
  {
    float bb = g0b[t];
    float a0 = bb, a1 = bb, a2 = bb, a3 = bb;
    for (int j = 0; j < 320; ++j) {
      float wv = g0w[j * 128 + t];
      a0 += xs[0][j] * wv; a1 += xs[1][j] * wv;
      a2 += xs[2][j] * wv; a3 += xs[3][j] * wv;
    }
    h1[0][t] = eluf(a0); h1[1][t] = eluf(a1);
    h1[2][t] = eluf(a2); h1[3][t] = eluf(a3);
  }
  __syncthreads();
  {
    float bb = g1b[t];
    float a0 = bb, a1 = bb, a2 = bb, a3 = bb;
    for (int j = 0; j < 128; ++j) {
      float wv = g1w[j * 128 + t];
      a0 += h1[0][j] * wv; a1 += h1[1][j] * wv;
      a2 += h1[2][j] * wv; a3 += h1[3][j] * wv;
    }
    h2[0][t] = eluf(a0); h2[1][t] = eluf(a1);
    h2[2][t] = eluf(a2); h2[3][t] = eluf(a3);
  }
  __syncthreads();
  if (t < 32) {
    int r = t >> 3, e = t & 7;
    float a = g2b[e];
    for (int j = 0; j < 128; ++j) a += h2[r][j] * g2w[j * 8 + e];
    lg[r][e] = a;
  }
  __syncthreads();
  if (t < 32) {
    int r = t >> 3, e = t & 7;
    float mx = lg[r][0];
#pragma unroll
    for (int i = 1; i < 8; ++i) mx = fmaxf(mx, lg[r][i]);
    float s = 0.f;
#pragma unroll
    for (int i = 0; i < 8; ++i) s += __expf(lg[r][i] - mx);
    float p = __expf(lg[r][e] - mx) / s;
    coeff[(size_t)(r0 + r) * 8 + e] = p;
    pr[r][e] = p;
  }
  __syncthreads();
  if (t < 32) {
    int r = t >> 3, e = t & 7;
    float pe = pr[r][e];
    float ratio = (e < 7) ? pe / fmaxf(pr[r][e + 1], 1e-30f) : pe;
    rat2[(size_t)(r0 + r) * 8 + e] = (e == 3 || e == 7) ? pe : ratio;
    rat4[(size_t)(r0 + r) * 8 + e] = (e & 1) ? pe : ratio;
  }
}

// ---------------------------------------------------------------------------
// LayerNorm over concat([z_row, prev_row]) -> out [B][J] bf16.
// Round 7: fuses the expert-split partial combine + bias-mix + ELU:
//   p1 != null : prev = elu(p0 + p1 + sum_e cf[row,e]*bias[e,:])
//   p1 == null : prev = p0 (raw, layer-0 path reading c)
// one row per 128-thread block
// ---------------------------------------------------------------------------
__global__ __launch_bounds__(128) void ln_concat_k(
    const float* __restrict__ z, const float* __restrict__ p0,
    const float* __restrict__ p1, const float* __restrict__ cf,
    const float* __restrict__ bias, ushort_t* __restrict__ out,
    int Pw, int J) {
  int row = blockIdx.x, t = threadIdx.x;
  float vals[9];
  int n = (J + 127) >> 7;
  float cr[8];
  if (p1) {
#pragma unroll
    for (int e = 0; e < 8; ++e) cr[e] = cf[(size_t)row * 8 + e];
  }
  float s = 0.f, s2 = 0.f;
  for (int k = 0; k < n; ++k) {
    int i = t + (k << 7);
    float x = 0.f;
    if (i < J) {
      if (i < 64) {
        x = z[(size_t)row * 64 + i];
      } else if (p1) {
        int j = i - 64;
        float v = p0[(size_t)row * Pw + j] + p1[(size_t)row * Pw + j];
#pragma unroll
        for (int e = 0; e < 8; ++e) v += cr[e] * bias[(size_t)e * Pw + j];
        x = eluf(v);
      } else {
        x = p0[(size_t)row * Pw + i - 64];
      }
    }
    vals[k] = x; s += x; s2 += x * x;
  }
  for (int off = 32; off > 0; off >>= 1) {
    s += __shfl_down(s, off);
    s2 += __shfl_down(s2, off);
  }
  __shared__ float red[4];
  int wid = t >> 6, lane = t & 63;
  if (lane == 0) { red[wid * 2] = s; red[wid * 2 + 1] = s2; }
  __syncthreads();
  float S = red[0] + red[2], S2 = red[1] + red[3];
  float inv = 1.f / (float)J;
  float m = S * inv;
  float var = S2 * inv - m * m;
  float rstd = rsqrtf(var + 1e-5f);
  for (int k = 0; k < n; ++k) {
    int i = t + (k << 7);
    if (i < J) out[(size_t)row * J + i] = f2b((vals[k] - m) * rstd);
  }
}

// ---------------------------------------------------------------------------
// Fused MoE GEMM, expert-split (round 7):
//   block (bt,ct,ez) computes the Horner-weighted sum over experts
//   [ez*ne, (ez+1)*ne) and stores a raw fp32 partial to outp[ez][B][K].
//   Bias-mix + ELU moved to ln_concat_k / combine4_k (they're BW-bound with
//   idle VALU; keeps this kernel's epilogue + LDS minimal).
// Rationale: previous grid (64,8) = 512 blocks = 2 blocks/CU (Occupancy 22.7%,
// MfmaUtil 20.4%) was grid-limited — the 2-barrier m97 structure needs ~3-4
// blocks/CU of implicit wave overlap to hide the vmcnt(0)+barrier drain.
// LDS trimmed to As+Wsm+scale_s = 37.4KB so 4 blocks/CU fit (was 46.6KB -> 3).
// 128x128 block tile, 4 waves of 64x64, mfma_f32_16x16x32_bf16, fp32 output.
// XCD mapping: flat id % 8 = bt % 8 -> all blocks sharing an A-panel (ct,ez
// sweep) land on one XCD; 8 A-tiles/XCD = 2.2MB, L2-resident across re-reads.
// ---------------------------------------------------------------------------
__device__ __forceinline__ void gload16(const void* g, void* l) {
  __builtin_amdgcn_global_load_lds(
      (const __attribute__((address_space(1))) void*)g,
      (__attribute__((address_space(3))) void*)l, 16, 0, 0);
}

__global__ __launch_bounds__(256, 4) void moe_gemm_k(
    const ushort_t* __restrict__ inp,   // [B][J] bf16 (LN'd concat)
    const ushort_t* __restrict__ wT,    // [K][E*J] bf16 (pre-transposed)
    const float* __restrict__ scales,   // [B][8] Horner boundary scales
    float* __restrict__ outp,           // [nez][B][K] fp32 partials
    int J, int K, int ne) {
  const int Kd = E_EXP * J;
  const int nj = J >> 6;
  __shared__ short As[16 * 512];      // [blk16][lane64][8 bf16] = 16KB
  __shared__ short Wsm[16 * 512];     // same layout for W            16KB
  __shared__ float scale_s[128 * 9];  // [row][e] stride 9 (bank-conflict pad)
  const int t = threadIdx.x;
  const int w = t >> 6, l = t & 63;
  const int bt = blockIdx.x, ct = blockIdx.y, ez = blockIdx.z;
  const int e0 = ez * ne;
  outp += (size_t)ez * (size_t)B_ROWS * (size_t)K;

#pragma unroll
  for (int i = 0; i < 4; ++i) {
    int idx = t + (i << 8);  // 0..1023
    int rw = idx >> 3, e = idx & 7;
    scale_s[rw * 9 + e] = scales[(size_t)(bt * 128 + rw) * 8 + e];
  }
  // (no explicit barrier needed: first scale_s read happens after the
  //  first jt-loop's __syncthreads pairs)

  // staging addresses: 16 A-blocks + 16 W-blocks of 1KB, 4+4 per wave.
  size_t aoff[4], woff[4];
#pragma unroll
  for (int i = 0; i < 4; ++i) {
    int bi = w * 4 + i;
    int sb = bi >> 3, rg = bi & 7;
    aoff[i] = (size_t)(bt * 128 + rg * 16 + (l & 15)) * J + (sb * 32 + (l >> 4) * 8);
    woff[i] = (size_t)(ct * 128 + rg * 16 + (l & 15)) * Kd + (size_t)e0 * J +
              (sb * 32 + (l >> 4) * 8);
  }

  f32x4 acc[4][4];
#pragma unroll
  for (int fm = 0; fm < 4; ++fm)
#pragma unroll
    for (int fn = 0; fn < 4; ++fn) acc[fm][fn] = (f32x4){0.f, 0.f, 0.f, 0.f};

  const int amBase = (w & 1) * 4;
  const int wnBase = (w >> 1) * 4;

  for (int le = 0; le < ne; ++le) {
    const int e = e0 + le;
    size_t ac0 = aoff[0], ac1 = aoff[1], ac2 = aoff[2], ac3 = aoff[3];
    for (int jt = 0; jt < nj; ++jt) {
      __syncthreads();  // previous slice's frag reads done before overwrite
      gload16(inp + ac0, As + (w * 4 + 0) * 512);
      gload16(inp + ac1, As + (w * 4 + 1) * 512);
      gload16(inp + ac2, As + (w * 4 + 2) * 512);
      gload16(inp + ac3, As + (w * 4 + 3) * 512);
      gload16(wT + woff[0], Wsm + (w * 4 + 0) * 512);
      gload16(wT + woff[1], Wsm + (w * 4 + 1) * 512);
      gload16(wT + woff[2], Wsm + (w * 4 + 2) * 512);
      gload16(wT + woff[3], Wsm + (w * 4 + 3) * 512);
      ac0 += 64; ac1 += 64; ac2 += 64; ac3 += 64;
      woff[0] += 64; woff[1] += 64; woff[2] += 64; woff[3] += 64;
      __syncthreads();  // drains vmcnt(0): staged data visible
#pragma unroll
      for (int sb = 0; sb < 2; ++sb) {
        bf16x8 af[4], wf[4];
#pragma unroll
        for (int fm = 0; fm < 4; ++fm)
          af[fm] = *(const bf16x8*)(As + (sb * 8 + amBase + fm) * 512 + l * 8);
#pragma unroll
        for (int fn = 0; fn < 4; ++fn)
          wf[fn] = *(const bf16x8*)(Wsm + (sb * 8 + wnBase + fn) * 512 + l * 8);
#pragma unroll
        for (int fm = 0; fm < 4; ++fm)
#pragma unroll
          for (int fn = 0; fn < 4; ++fn)
            acc[fm][fn] = __builtin_amdgcn_mfma_f32_16x16x32_bf16(
                af[fm], wf[fn], acc[fm][fn], 0, 0, 0);
      }
    }
    // Horner boundary rescale within the subset:
    //   le < ne-1: acc *= c_e/c_{e+1};  le == ne-1: acc *= c_e
    // (scale_s pre-encodes exactly this for the static split)
#pragma unroll
    for (int fm = 0; fm < 4; ++fm) {
      int rbase = (w & 1) * 64 + fm * 16 + ((l >> 4) << 2);
#pragma unroll
      for (int rr = 0; rr < 4; ++rr) {
        float rv = scale_s[(rbase + rr) * 9 + e];
#pragma unroll
        for (int fn = 0; fn < 4; ++fn) acc[fm][fn][rr] *= rv;
      }
    }
  }

  // epilogue: raw fp32 partial store (bias/ELU handled downstream)
  const int wm = (w & 1) * 64, wn = (w >> 1) * 64;
#pragma unroll
  for (int fm = 0; fm < 4; ++fm) {
#pragma unroll
    for (int rr = 0; rr < 4; ++rr) {
      int row = wm + fm * 16 + ((l >> 4) << 2) + rr;
      size_t orow = (size_t)(bt * 128 + row) * K + ct * 128;
#pragma unroll
      for (int fn = 0; fn < 4; ++fn) {
        int col = wn + fn * 16 + (l & 15);
        outp[orow + col] = acc[fm][fn][rr];
      }
    }
  }
}

// ---------------------------------------------------------------------------
// Final combine for layer 3 (4-way expert split, K=512, no activation):
//   out = p0+p1+p2+p3 + coeff@bias
// ---------------------------------------------------------------------------
__global__ __launch_bounds__(256) void combine4_k(
    const float* __restrict__ pb, const float* __restrict__ cf,
    const float* __restrict__ bias, float* __restrict__ out, int K) {
  size_t i4 = (size_t)blockIdx.x * 256 + threadIdx.x;
  size_t total = (size_t)B_ROWS * (size_t)K;
  size_t base = i4 * 4;
  if (base >= total) return;
  int row = (int)(base / (size_t)K);
  int col = (int)(base % (size_t)K);
  size_t s4 = total >> 2;  // partial stride in f32x4 units
  const f32x4* p4 = (const f32x4*)pb;
  f32x4 v = p4[i4] + p4[i4 + s4] + p4[i4 + 2 * s4] + p4[i4 + 3 * s4];
#pragma unroll
  for (int e = 0; e < 8; ++e) {
    float ce = cf[(size_t)row * 8 + e];
    f32x4 bv = *(const f32x4*)(bias + (size_t)e * K + col);
    v += ce * bv;
  }
  ((f32x4*)out)[i4] = v;
}

// ---------------------------------------------------------------------------
extern "C" void kernel_launch(void* const* d_in, const int* in_sizes, int n_in,
                              void* d_out, int out_size, void* d_ws, size_t ws_size,
                              hipStream_t stream) {
  const float* z   = (const float*)d_in[0];
  const float* c   = (const float*)d_in[1];
  const float* g0w = (const float*)d_in[2];
  const float* g0b = (const float*)d_in[3];
  const float* g1w = (const float*)d_in[4];
  const float* g1b = (const float*)d_in[5];
  const float* g2w = (const float*)d_in[6];
  const float* g2b = (const float*)d_in[7];
  const float* w0  = (const float*)d_in[8];
  const float* b0  = (const float*)d_in[9];
  const float* w1  = (const float*)d_in[10];
  const float* b1  = (const float*)d_in[11];
  const float* w2  = (const float*)d_in[12];
  const float* b2  = (const float*)d_in[13];
  const float* w3  = (const float*)d_in[14];
  const float* b3  = (const float*)d_in[15];

  char* ws = (char*)d_ws;
  size_t o = 0;
  auto alloc = [&](size_t bytes) {
    void* p = ws + o;
    o += (bytes + 255) & ~(size_t)255;
    return p;
  };
  ushort_t* wT0 = (ushort_t*)alloc((size_t)2560 * 1024 * 2);
  ushort_t* wT1 = (ushort_t*)alloc((size_t)8704 * 1024 * 2);
  ushort_t* wT2 = (ushort_t*)alloc((size_t)8704 * 1024 * 2);
  ushort_t* wT3 = (ushort_t*)alloc((size_t)8704 * 512 * 2);
  float*    cf   = (float*)alloc((size_t)B_ROWS * 8 * 4);
  float*    rat2 = (float*)alloc((size_t)B_ROWS * 8 * 4);
  float*    rat4 = (float*)alloc((size_t)B_ROWS * 8 * 4);
  ushort_t* inp  = (ushort_t*)alloc((size_t)B_ROWS * 1088 * 2);
  float*    pb   = (float*)alloc((size_t)2 * B_ROWS * 1024 * 4);  // partials

  dim3 tb(64, 16);
  transpose_k<<<dim3(1024 / 64, 2560 / 64), tb, 0, stream>>>(w0, wT0, 2560, 1024);
  transpose_k<<<dim3(1024 / 64, 8704 / 64), tb, 0, stream>>>(w1, wT1, 8704, 1024);
  transpose_k<<<dim3(1024 / 64, 8704 / 64), tb, 0, stream>>>(w2, wT2, 8704, 1024);
  transpose_k<<<dim3(512 / 64, 8704 / 64), tb, 0, stream>>>(w3, wT3, 8704, 512);

  gate_k<<<B_ROWS / 4, 128, 0, stream>>>(z, c, g0w, g0b, g1w, g1b, g2w, g2b,
                                         cf, rat2, rat4);

  float* p1v = pb + (size_t)B_ROWS * 1024;

  // layer 0: J=320, K=1024, 2-way expert split (ne=4)
  ln_concat_k<<<B_ROWS, 128, 0, stream>>>(z, c, nullptr, nullptr, nullptr,
                                          inp, 256, 320);
  moe_gemm_k<<<dim3(64, 8, 2), 256, 0, stream>>>(inp, wT0, rat2, pb, 320, 1024, 4);
  // layer 1: J=1088, K=1024 (ln fuses combine + b0-mix + elu)
  ln_concat_k<<<B_ROWS, 128, 0, stream>>>(z, pb, p1v, cf, b0, inp, 1024, 1088);
  moe_gemm_k<<<dim3(64, 8, 2), 256, 0, stream>>>(inp, wT1, rat2, pb, 1088, 1024, 4);
  // layer 2
  ln_concat_k<<<B_ROWS, 128, 0, stream>>>(z, pb, p1v, cf, b1, inp, 1024, 1088);
  moe_gemm_k<<<dim3(64, 8, 2), 256, 0, stream>>>(inp, wT2, rat2, pb, 1088, 1024, 4);
  // layer 3: J=1088, K=512, 4-way expert split (ne=2), no act
  ln_concat_k<<<B_ROWS, 128, 0, stream>>>(z, pb, p1v, cf, b2, inp, 1024, 1088);
  moe_gemm_k<<<dim3(64, 4, 4), 256, 0, stream>>>(inp, wT3, rat4, pb, 1088, 512, 2);
  combine4_k<<<(B_ROWS * 512) / 1024, 256, 0, stream>>>(pb, cf, b3,
                                                        (float*)d_out, 512);
}